// Round 1
// baseline (2736.326 us; speedup 1.0000x reference)
//
#include <hip/hip_runtime.h>
#include <hip/hip_bf16.h>
#include <math.h>

#define EPSF 1e-12f
#define H 256
#define TSTEPS 4096
#define BATCH 32
#define TB (TSTEPS*BATCH)
#define BH (BATCH*H)

typedef _Float16 h2 __attribute__((ext_vector_type(2)));

#if defined(__has_builtin)
#if __has_builtin(__builtin_amdgcn_fdot2)
#define FDOT2(a, b, c) __builtin_amdgcn_fdot2((a), (b), (c), false)
#endif
#endif
#ifndef FDOT2
#define FDOT2(a, b, c) fmaf((float)(a).y, (float)(b).y, fmaf((float)(a).x, (float)(b).x, (c)))
#endif

#define BC(u) __builtin_bit_cast(h2, (u))

// R6: barrier WITHOUT vmcnt(0) drain. __syncthreads() emits
// "s_waitcnt vmcnt(0) expcnt(0) lgkmcnt(0); s_barrier", which per-step
// drains the pre-prefetch HBM load (~900cy latency, only ~400cy hidden)
// and the h_t global-store ack (~300cy). LDS ordering (hbuf/part) only
// needs lgkmcnt(0). Global-load correctness is preserved by the
// compiler's own counted vmcnt(N) before each USE of the loaded value.
// sched_barrier(0) on both sides per guide rule #18 (hipcc may hoist
// register-only ops past inline-asm waitcnt despite "memory" clobber).
__device__ __forceinline__ void bar_nodrain() {
  __builtin_amdgcn_sched_barrier(0);
  asm volatile("s_waitcnt lgkmcnt(0)" ::: "memory");
  __builtin_amdgcn_s_barrier();
  __builtin_amdgcn_sched_barrier(0);
}

// ---------------- block-wide sum over 256 threads (4 waves) ----------------
__device__ __forceinline__ float block_sum256(float v, float* red) {
  #pragma unroll
  for (int o = 32; o > 0; o >>= 1) v += __shfl_down(v, o, 64);
  __syncthreads();                       // protect red from previous use
  if ((threadIdx.x & 63) == 0) red[threadIdx.x >> 6] = v;
  __syncthreads();
  return red[0] + red[1] + red[2] + red[3];
}

// ---------------- kernel 1: spectral sigmas + normalized bias ----------------
// wsc[0..255] = b_sn, wsc[256] = 1/sigma_ih, wsc[257] = 1/sigma_hh
__global__ __launch_bounds__(256) void k_prep(
    const float* __restrict__ w_ih, const float* __restrict__ w_hh,
    const float* __restrict__ b_ih, const float* __restrict__ b_hh,
    const float* __restrict__ u_ih, const float* __restrict__ u_hh,
    float* __restrict__ wsc) {
  __shared__ float red[4];
  __shared__ float ubuf[H];
  __shared__ float vbuf[H];
  const int tid = threadIdx.x;

  float inv_sig[2];
  const float* Ws[2] = {w_ih, w_hh};
  const float* Us[2] = {u_ih, u_hh};
  #pragma unroll 1
  for (int m = 0; m < 2; m++) {
    const float* W = Ws[m];
    // u_n = u / (||u|| + eps)
    float uv = Us[m][tid];
    float nu = sqrtf(block_sum256(uv * uv, red));
    ubuf[tid] = uv / (nu + EPSF);
    __syncthreads();
    // v = l2norm(W^T @ u_n)   (column reads: coalesced across lanes)
    float vt = 0.f;
    for (int h = 0; h < H; h++) vt = fmaf(W[h * H + tid], ubuf[h], vt);
    float nv = sqrtf(block_sum256(vt * vt, red));
    vbuf[tid] = vt / (nv + EPSF);
    __syncthreads();
    // wv = W @ v ; sigma = ||wv||^2 / (||wv|| + eps)  (== u_new . wv exactly)
    float wv = 0.f;
    const float* wr = W + (size_t)tid * H;
    for (int i = 0; i < H; i++) wv = fmaf(wr[i], vbuf[i], wv);
    float n2 = block_sum256(wv * wv, red);
    float sigma = n2 / (sqrtf(n2) + EPSF);
    inv_sig[m] = 1.f / sigma;
  }
  // b_sn = b_ih/(||b_ih||+eps) + b_hh/(||b_hh||+eps)
  float bi = b_ih[tid], bh = b_hh[tid];
  float nbi = sqrtf(block_sum256(bi * bi, red));
  float nbh = sqrtf(block_sum256(bh * bh, red));
  wsc[tid] = bi / (nbi + EPSF) + bh / (nbh + EPSF);
  if (tid == 0) { wsc[H] = inv_sig[0]; wsc[H + 1] = inv_sig[1]; }
}

// ---------------- kernel 2: pre = x @ W_ih_sn^T + b_sn -> out[0:T*B*H] -------
// block handles 32 rows of (T*B); thread = output h column.
__global__ __launch_bounds__(256) void k_pre(
    const float* __restrict__ x, const float* __restrict__ w_ih,
    const float* __restrict__ wsc, float* __restrict__ pre) {
  __shared__ float xs[32 * 256];        // 32 KB x-tile
  const int tid = threadIdx.x;
  const size_t m0 = (size_t)blockIdx.x * 32;

  // stage 32 rows of x (coalesced float4)
  const float4* xp = (const float4*)(x + m0 * H);
  float4* xsv = (float4*)xs;
  #pragma unroll
  for (int j = 0; j < 8; j++) xsv[j * 256 + tid] = xp[j * 256 + tid];
  __syncthreads();

  float acc[32];
  #pragma unroll
  for (int m = 0; m < 32; m++) acc[m] = 0.f;

  const float* wrow = w_ih + (size_t)tid * H;
  #pragma unroll 1
  for (int kb = 0; kb < 256; kb += 8) {
    float4 wa = *(const float4*)(wrow + kb);
    float4 wb = *(const float4*)(wrow + kb + 4);
    #pragma unroll
    for (int m = 0; m < 32; m++) {
      const float* xr = xs + m * 256 + kb;
      float4 xa = *(const float4*)xr;        // LDS broadcast (all lanes same addr)
      float4 xb = *(const float4*)(xr + 4);
      float a = acc[m];
      a = fmaf(xa.x, wa.x, a); a = fmaf(xa.y, wa.y, a);
      a = fmaf(xa.z, wa.z, a); a = fmaf(xa.w, wa.w, a);
      a = fmaf(xb.x, wb.x, a); a = fmaf(xb.y, wb.y, a);
      a = fmaf(xb.z, wb.z, a); a = fmaf(xb.w, wb.w, a);
      acc[m] = a;
    }
  }
  const float inv_s = wsc[H];
  const float bsn = wsc[tid];
  #pragma unroll
  for (int m = 0; m < 32; m++)
    pre[(m0 + m) * H + tid] = fmaf(acc[m], inv_s, bsn);   // coalesced store
}

// ---------------- kernel 3: sequential scan, one block per batch element ----
// R5: LDS-broadcast traffic is the limiter (R4: 128 KB/step ≈ 1359 cy).
// 512 threads = 8 waves; wave cg owns 32 h-columns; lane q owns 4 rows
// (4q..4q+3). Each loaded h value feeds 4 dot products (4x LDS traffic cut:
// 32 KB/step). W slice = 4x16 h2 = 64 VGPRs. part[8][256] reduced by
// 256 threads (thread = row), conflict-free both phases.
// R6: in-loop barriers no longer drain vmcnt — pre-prefetch loads and the
// h_t store stay in flight across the barrier (T4 lesson). Expect the
// ~800cy/step drain stall to vanish.
__global__ __launch_bounds__(512, 1) void k_scan(
    const float* __restrict__ state, const float* __restrict__ w_hh,
    const float* __restrict__ wsc, float* __restrict__ out) {
  __shared__ __align__(16) _Float16 hbuf[2][H];   // 512 B each
  __shared__ __align__(16) float part[8][H];      // 8 KB
  const int tid = threadIdx.x;
  const int cg = tid >> 6;       // 0..7 == wave id == col group (32 cols)
  const int q  = tid & 63;       // lane; owns rows 4q..4q+3
  const int r0 = q << 2;
  const int b = blockIdx.x;
  const float inv_s = wsc[H + 1];

  // stage W[4q+i][cg*32 .. +31] as 4x16 packed f16x2, pre-scaled by 1/sigma
  h2 wreg[4][16];
  #pragma unroll
  for (int i = 0; i < 4; i++) {
    const float* wr = w_hh + (size_t)(r0 + i) * H + (cg << 5);
    #pragma unroll
    for (int c = 0; c < 16; c++) {
      float2 wv = *(const float2*)(wr + 2 * c);
      wreg[i][c] = h2{(_Float16)(wv.x * inv_s), (_Float16)(wv.y * inv_s)};
    }
  }

  if (tid < H) hbuf[0][tid] = (_Float16)state[b * H + tid];
  float* outb = out + (size_t)b * H + tid;       // only dereferenced if tid<H
  float pre0 = 0.f, pre1 = 0.f;
  if (tid < H) { pre0 = outb[0]; pre1 = outb[BH]; }   // prefetch depth 2
  bar_nodrain();

  float hn = 0.f;
  #pragma unroll 1
  for (int t = 0; t < TSTEPS; t++) {
    float pre2 = 0.f;
    if (tid < H) {
      int tn = (t + 2 <= TSTEPS) ? (t + 2) : TSTEPS;   // clamp into h_last region
      pre2 = outb[(size_t)tn * BH];
    }

    // 32 f16 h-values = 4 uint4 LDS broadcast reads (wave-uniform addr)
    const uint4* hb = (const uint4*)(hbuf[t & 1] + (cg << 5));
    uint4 q0 = hb[0], q1 = hb[1], q2 = hb[2], q3 = hb[3];

    float acc[4];
    #pragma unroll
    for (int i = 0; i < 4; i++) {
      float a = 0.f;
      a = FDOT2(wreg[i][ 0], BC(q0.x), a);
      a = FDOT2(wreg[i][ 1], BC(q0.y), a);
      a = FDOT2(wreg[i][ 2], BC(q0.z), a);
      a = FDOT2(wreg[i][ 3], BC(q0.w), a);
      a = FDOT2(wreg[i][ 4], BC(q1.x), a);
      a = FDOT2(wreg[i][ 5], BC(q1.y), a);
      a = FDOT2(wreg[i][ 6], BC(q1.z), a);
      a = FDOT2(wreg[i][ 7], BC(q1.w), a);
      a = FDOT2(wreg[i][ 8], BC(q2.x), a);
      a = FDOT2(wreg[i][ 9], BC(q2.y), a);
      a = FDOT2(wreg[i][10], BC(q2.z), a);
      a = FDOT2(wreg[i][11], BC(q2.w), a);
      a = FDOT2(wreg[i][12], BC(q3.x), a);
      a = FDOT2(wreg[i][13], BC(q3.y), a);
      a = FDOT2(wreg[i][14], BC(q3.z), a);
      a = FDOT2(wreg[i][15], BC(q3.w), a);
      acc[i] = a;
    }
    // conflict-free b128 store: lanes write contiguous 16B (part[cg][4q..4q+3])
    *(float4*)&part[cg][r0] = make_float4(acc[0], acc[1], acc[2], acc[3]);
    bar_nodrain();

    if (tid < H) {                       // thread = row; 2-way-free b32 reads
      float s = pre0;
      #pragma unroll
      for (int g = 0; g < 8; g++) s += part[g][tid];
      float sc = fminf(fmaxf(s, -15.f), 15.f);
      float e = __expf(2.f * sc);
      hn = __fdividef(e - 1.f, e + 1.f); // tanh
      outb[(size_t)t * BH] = hn;         // overwrite pre slot with h_t (f32)
      hbuf[(t + 1) & 1][tid] = (_Float16)hn;  // publish f16 h for next step
    }
    bar_nodrain();
    pre0 = pre1; pre1 = pre2;
  }
  if (tid < H) out[(size_t)TSTEPS * BH + b * H + tid] = hn;  // h_last tail
}

// ---------------- launcher ---------------------------------------------------
extern "C" void kernel_launch(void* const* d_in, const int* in_sizes, int n_in,
                              void* d_out, int out_size, void* d_ws, size_t ws_size,
                              hipStream_t stream) {
  const float* x     = (const float*)d_in[0];
  const float* state = (const float*)d_in[1];
  const float* w_ih  = (const float*)d_in[2];
  const float* w_hh  = (const float*)d_in[3];
  const float* b_ih  = (const float*)d_in[4];
  const float* b_hh  = (const float*)d_in[5];
  const float* u_ih  = (const float*)d_in[6];
  const float* u_hh  = (const float*)d_in[7];
  float* out = (float*)d_out;
  float* wsc = (float*)d_ws;   // 258 floats of scratch

  k_prep<<<1, 256, 0, stream>>>(w_ih, w_hh, b_ih, b_hh, u_ih, u_hh, wsc);
  k_pre<<<TB / 32, 256, 0, stream>>>(x, w_ih, wsc, out);
  k_scan<<<BATCH, 512, 0, stream>>>(state, w_hh, wsc, out);
}

// Round 2
// 2728.050 us; speedup vs baseline: 1.0030x; 1.0030x over previous
//
#include <hip/hip_runtime.h>
#include <hip/hip_bf16.h>
#include <math.h>

#define EPSF 1e-12f
#define H 256
#define TSTEPS 4096
#define BATCH 32
#define TB (TSTEPS*BATCH)
#define BH (BATCH*H)

typedef _Float16 h2 __attribute__((ext_vector_type(2)));

#if defined(__has_builtin)
#if __has_builtin(__builtin_amdgcn_fdot2)
#define FDOT2(a, b, c) __builtin_amdgcn_fdot2((a), (b), (c), false)
#endif
#endif
#ifndef FDOT2
#define FDOT2(a, b, c) fmaf((float)(a).y, (float)(b).y, fmaf((float)(a).x, (float)(b).x, (c)))
#endif

#define BC(u) __builtin_bit_cast(h2, (u))

// DPP cross-lane: result = src from permuted lane (VALU pipe, no LDS traffic)
#define DPPF(x, ctrl) __builtin_bit_cast(float, __builtin_amdgcn_update_dpp( \
    0, __builtin_bit_cast(int, (x)), (ctrl), 0xf, 0xf, true))
#define DPP_QUAD_XOR1 0xB1   // quad_perm [1,0,3,2]
#define DPP_QUAD_XOR2 0x4E   // quad_perm [2,3,0,1]
#define DPP_HALF_MIRROR 0x141
#define DPP_ROW_MIRROR  0x140

// R7: barrier without vmcnt drain (lgkmcnt only). R6 showed the drain was
// NOT the stall, but this form is still >= __syncthreads; keep it.
__device__ __forceinline__ void bar_nodrain() {
  __builtin_amdgcn_sched_barrier(0);
  asm volatile("s_waitcnt lgkmcnt(0)" ::: "memory");
  __builtin_amdgcn_s_barrier();
  __builtin_amdgcn_sched_barrier(0);
}

// ---------------- block-wide sum over 256 threads (4 waves) ----------------
__device__ __forceinline__ float block_sum256(float v, float* red) {
  #pragma unroll
  for (int o = 32; o > 0; o >>= 1) v += __shfl_down(v, o, 64);
  __syncthreads();
  if ((threadIdx.x & 63) == 0) red[threadIdx.x >> 6] = v;
  __syncthreads();
  return red[0] + red[1] + red[2] + red[3];
}

// ---------------- kernel 1: spectral sigmas + normalized bias ----------------
// wsc[0..255] = b_sn, wsc[256] = 1/sigma_ih, wsc[257] = 1/sigma_hh
__global__ __launch_bounds__(256) void k_prep(
    const float* __restrict__ w_ih, const float* __restrict__ w_hh,
    const float* __restrict__ b_ih, const float* __restrict__ b_hh,
    const float* __restrict__ u_ih, const float* __restrict__ u_hh,
    float* __restrict__ wsc) {
  __shared__ float red[4];
  __shared__ float ubuf[H];
  __shared__ float vbuf[H];
  const int tid = threadIdx.x;

  float inv_sig[2];
  const float* Ws[2] = {w_ih, w_hh};
  const float* Us[2] = {u_ih, u_hh};
  #pragma unroll 1
  for (int m = 0; m < 2; m++) {
    const float* W = Ws[m];
    float uv = Us[m][tid];
    float nu = sqrtf(block_sum256(uv * uv, red));
    ubuf[tid] = uv / (nu + EPSF);
    __syncthreads();
    float vt = 0.f;
    for (int h = 0; h < H; h++) vt = fmaf(W[h * H + tid], ubuf[h], vt);
    float nv = sqrtf(block_sum256(vt * vt, red));
    vbuf[tid] = vt / (nv + EPSF);
    __syncthreads();
    float wv = 0.f;
    const float* wr = W + (size_t)tid * H;
    for (int i = 0; i < H; i++) wv = fmaf(wr[i], vbuf[i], wv);
    float n2 = block_sum256(wv * wv, red);
    float sigma = n2 / (sqrtf(n2) + EPSF);
    inv_sig[m] = 1.f / sigma;
  }
  float bi = b_ih[tid], bh = b_hh[tid];
  float nbi = sqrtf(block_sum256(bi * bi, red));
  float nbh = sqrtf(block_sum256(bh * bh, red));
  wsc[tid] = bi / (nbi + EPSF) + bh / (nbh + EPSF);
  if (tid == 0) { wsc[H] = inv_sig[0]; wsc[H + 1] = inv_sig[1]; }
}

// ---------------- kernel 2: pre = x @ W_ih_sn^T + b_sn -> out[0:T*B*H] -------
__global__ __launch_bounds__(256) void k_pre(
    const float* __restrict__ x, const float* __restrict__ w_ih,
    const float* __restrict__ wsc, float* __restrict__ pre) {
  __shared__ float xs[32 * 256];        // 32 KB x-tile
  const int tid = threadIdx.x;
  const size_t m0 = (size_t)blockIdx.x * 32;

  const float4* xp = (const float4*)(x + m0 * H);
  float4* xsv = (float4*)xs;
  #pragma unroll
  for (int j = 0; j < 8; j++) xsv[j * 256 + tid] = xp[j * 256 + tid];
  __syncthreads();

  float acc[32];
  #pragma unroll
  for (int m = 0; m < 32; m++) acc[m] = 0.f;

  const float* wrow = w_ih + (size_t)tid * H;
  #pragma unroll 1
  for (int kb = 0; kb < 256; kb += 8) {
    float4 wa = *(const float4*)(wrow + kb);
    float4 wb = *(const float4*)(wrow + kb + 4);
    #pragma unroll
    for (int m = 0; m < 32; m++) {
      const float* xr = xs + m * 256 + kb;
      float4 xa = *(const float4*)xr;
      float4 xb = *(const float4*)(xr + 4);
      float a = acc[m];
      a = fmaf(xa.x, wa.x, a); a = fmaf(xa.y, wa.y, a);
      a = fmaf(xa.z, wa.z, a); a = fmaf(xa.w, wa.w, a);
      a = fmaf(xb.x, wb.x, a); a = fmaf(xb.y, wb.y, a);
      a = fmaf(xb.z, wb.z, a); a = fmaf(xb.w, wb.w, a);
      acc[m] = a;
    }
  }
  const float inv_s = wsc[H];
  const float bsn = wsc[tid];
  #pragma unroll
  for (int m = 0; m < 32; m++)
    pre[(m0 + m) * H + tid] = fmaf(acc[m], inv_s, bsn);
}

// swizzle a byte offset within a 512B hbuf: XOR bit8 into bit6 (moves 64B
// granules so the 16 32B k-lines spread 2-way instead of 4-way over banks)
__device__ __forceinline__ int swz(int a) { return a ^ (((a >> 8) & 1) << 6); }

// ---------------- kernel 3: sequential scan, one block per batch element ----
// R7 restructure: wave cg owns ROWS [32cg,32cg+32); lane = (rgrp=q>>4 row
// octet, kseg=q&15 16-elem k-chunk) -> 8 rows x 16 cols = 64 FDOT2/lane.
// h-read: 32 B/lane (2x b128, swizzled) = 16 KB/step (was 32 KB).
// Reduction over the 16 ksegs = one DPP row: reduce-scatter
// (row_mirror/half_mirror/quad_perm) on the VALU pipe — part[] round trip,
// barrier #1 and the half-idle reduce phase are all deleted. One barrier/step.
__global__ __launch_bounds__(512, 1) void k_scan(
    const float* __restrict__ state, const float* __restrict__ w_hh,
    const float* __restrict__ wsc, float* __restrict__ out) {
  __shared__ __align__(16) _Float16 hbuf[2][H];   // 512 B each, 64B-swizzled
  const int tid = threadIdx.x;
  const int cg   = tid >> 6;      // wave id: rows [32cg, 32cg+32)
  const int q    = tid & 63;
  const int rgrp = q >> 4;        // row octet: rows 32cg+8rgrp+[0,8)
  const int kseg = q & 15;        // k in [16kseg, 16kseg+16)
  // row this lane ends up owning after the reduce-scatter tree
  const int jrow = 4 * ((q >> 3) & 1) + 2 * ((q >> 2) & 1) + ((q >> 1) & 1);
  const int myrow = (cg << 5) + (rgrp << 3) + jrow;
  const int b = blockIdx.x;
  const float inv_s = wsc[H + 1];
  const bool hb3 = (q >> 3) & 1, hb2 = (q >> 2) & 1, hb1 = (q >> 1) & 1;

  // stage W[32cg+8rgrp+i][16kseg + 2c..2c+1], pre-scaled by 1/sigma: 64 VGPR
  h2 wreg[8][8];
  #pragma unroll
  for (int i = 0; i < 8; i++) {
    const float* wr = w_hh + (size_t)((cg << 5) + (rgrp << 3) + i) * H + (kseg << 4);
    #pragma unroll
    for (int c = 0; c < 8; c++) {
      float2 wv = *(const float2*)(wr + 2 * c);
      wreg[i][c] = h2{(_Float16)(wv.x * inv_s), (_Float16)(wv.y * inv_s)};
    }
  }

  // constant per-lane LDS offsets (swizzled)
  const int a0s = swz(kseg << 5);
  const int a1s = swz((kseg << 5) + 16);
  const int woff = swz(myrow * 2);

  if (tid < H)
    *(_Float16*)((char*)&hbuf[0][0] + swz(tid * 2)) = (_Float16)state[b * H + tid];

  // per-row pre prefetch (depth 2); lane pairs duplicate-load (coalesced)
  const float* pbase = out + (size_t)b * H + myrow;
  float pre0 = pbase[0], pre1 = pbase[BH];
  bar_nodrain();

  float hn = 0.f;
  #pragma unroll 1
  for (int t = 0; t < TSTEPS; t++) {
    int tn = (t + 2 <= TSTEPS) ? (t + 2) : TSTEPS;   // clamp into h_last region
    float pre2 = pbase[(size_t)tn * BH];

    const char* hb = (const char*)&hbuf[t & 1][0];
    uint4 q0 = *(const uint4*)(hb + a0s);
    uint4 q1 = *(const uint4*)(hb + a1s);

    float acc[8];
    #pragma unroll
    for (int i = 0; i < 8; i++) {
      float a = 0.f;
      a = FDOT2(wreg[i][0], BC(q0.x), a);
      a = FDOT2(wreg[i][1], BC(q0.y), a);
      a = FDOT2(wreg[i][2], BC(q0.z), a);
      a = FDOT2(wreg[i][3], BC(q0.w), a);
      a = FDOT2(wreg[i][4], BC(q1.x), a);
      a = FDOT2(wreg[i][5], BC(q1.y), a);
      a = FDOT2(wreg[i][6], BC(q1.z), a);
      a = FDOT2(wreg[i][7], BC(q1.w), a);
      acc[i] = a;
    }

    // reduce-scatter over 16 ksegs (one DPP row), all-VALU.
    // level D (partner bit3 flipped via row_mirror): 8 -> 4 values
    float v0, v1, v2, v3;
    { float k0 = hb3 ? acc[4] : acc[0], s0 = hb3 ? acc[0] : acc[4];
      float k1 = hb3 ? acc[5] : acc[1], s1 = hb3 ? acc[1] : acc[5];
      float k2 = hb3 ? acc[6] : acc[2], s2 = hb3 ? acc[2] : acc[6];
      float k3 = hb3 ? acc[7] : acc[3], s3 = hb3 ? acc[3] : acc[7];
      v0 = k0 + DPPF(s0, DPP_ROW_MIRROR);
      v1 = k1 + DPPF(s1, DPP_ROW_MIRROR);
      v2 = k2 + DPPF(s2, DPP_ROW_MIRROR);
      v3 = k3 + DPPF(s3, DPP_ROW_MIRROR); }
    // level C (bit2 flipped via row_half_mirror): 4 -> 2
    float u0, u1;
    { float k0 = hb2 ? v2 : v0, s0 = hb2 ? v0 : v2;
      float k1 = hb2 ? v3 : v1, s1 = hb2 ? v1 : v3;
      u0 = k0 + DPPF(s0, DPP_HALF_MIRROR);
      u1 = k1 + DPPF(s1, DPP_HALF_MIRROR); }
    // level B (bit1 flipped via quad_perm xor2): 2 -> 1
    float ssum;
    { float k0 = hb1 ? u1 : u0, s0 = hb1 ? u0 : u1;
      ssum = k0 + DPPF(s0, DPP_QUAD_XOR2); }
    // level A: lane pairs hold the same row -> plain butterfly add
    ssum += DPPF(ssum, DPP_QUAD_XOR1);

    float s = ssum + pre0;
    float sc = fminf(fmaxf(s, -15.f), 15.f);
    float e = __expf(2.f * sc);
    hn = __fdividef(e - 1.f, e + 1.f);   // tanh

    if (!(q & 1)) {                      // even lane of each pair publishes
      *(_Float16*)((char*)&hbuf[(t + 1) & 1][0] + woff) = (_Float16)hn;
      out[(size_t)t * BH + b * H + myrow] = hn;   // overwrite pre slot (f32)
    }
    bar_nodrain();                       // single barrier per step
    pre0 = pre1; pre1 = pre2;
  }
  if (!(q & 1)) out[(size_t)TSTEPS * BH + b * H + myrow] = hn;   // h_last
}

// ---------------- launcher ---------------------------------------------------
extern "C" void kernel_launch(void* const* d_in, const int* in_sizes, int n_in,
                              void* d_out, int out_size, void* d_ws, size_t ws_size,
                              hipStream_t stream) {
  const float* x     = (const float*)d_in[0];
  const float* state = (const float*)d_in[1];
  const float* w_ih  = (const float*)d_in[2];
  const float* w_hh  = (const float*)d_in[3];
  const float* b_ih  = (const float*)d_in[4];
  const float* b_hh  = (const float*)d_in[5];
  const float* u_ih  = (const float*)d_in[6];
  const float* u_hh  = (const float*)d_in[7];
  float* out = (float*)d_out;
  float* wsc = (float*)d_ws;   // 258 floats of scratch

  k_prep<<<1, 256, 0, stream>>>(w_ih, w_hh, b_ih, b_hh, u_ih, u_hh, wsc);
  k_pre<<<TB / 32, 256, 0, stream>>>(x, w_ih, wsc, out);
  k_scan<<<BATCH, 512, 0, stream>>>(state, w_hh, wsc, out);
}